// Round 6
// baseline (7969.753 us; speedup 1.0000x reference)
//
#include <hip/hip_runtime.h>
#include <hip/hip_fp16.h>
#include <math.h>

#define NVIEW 720
#define NDCT  1024
#define NZ    32
#define NX    512
#define NY    512

#define BX 16        // block tile x
#define BY 16        // block tile y
#define ZG 16        // z per block (z-split factor 2)
#define ZLDS 12      // z served from LDS (3 x ds_read_b128)
#define NR 24        // staged detector rows (16x16 tile i0 spread <= 23)
#define RSTRIDE 12   // dwords per staged row (48 B, 16B-aligned). Chunk bank-group
                     // = (3r+c) mod 8, injective in r mod 8 -> only dr in {8,16}
                     // alias (mostly 2-way, ~free). No swizzle (R3 lesson).

typedef unsigned int uint;

__device__ __forceinline__ __half2 u2h(uint u) {
    union { uint u; __half2 h; } x; x.u = u; return x.h;
}
__device__ __forceinline__ uint f16b(float f) {
    return (uint)__half_as_ushort(__float2half_rn(f));
}

// Workspace layout:
//  P[((v*1024 + i)*2 + h)*12 + dw], dw 0..5 = f16-pair words (g0[z],g0[z+1]),
//    dw 6..11 = (d[z],d[z+1]), z = h*16 + 2*dw(-12) .. covers z in [h*16, h*16+12)
//  Q[(((v*2 + h)*2 + k)*1024 + i)*2 + zp]: k0=g0-pairs,k1=d-pairs, z in [h*16+12, h*16+16)
// g0 = p[i], d = p[i+1]-p[i]; lo half = even z.
// Input x: (Z=32,1,NVIEW,NDCT); proj[v][z][i] = x[z][0][v][i].
__global__ __launch_bounds__(64) void pack_kernel(const float* __restrict__ x,
                                                  uint* __restrict__ P,
                                                  uint* __restrict__ Q) {
    __shared__ uint tr[64 * 33];             // [i_local][z]: lo=f16(g0), hi=f16(d)
    const int l  = threadIdx.x;              // 0..63
    const int v  = blockIdx.x;               // 0..719
    const int ib = blockIdx.y * 64;          // i block base
    const bool last = (ib + 64 >= NDCT);
    const float* rowbase = x + (size_t)v * NDCT + ib;

    float pre = 0.0f;                        // boundary value i=ib+64, z=lane
    if (l < NZ && !last) pre = rowbase[(size_t)l * (NVIEW * NDCT) + 64];

    for (int z = 0; z < NZ; ++z) {
        const float* r = rowbase + (size_t)z * (NVIEW * NDCT);
        float a   = r[l];                    // coalesced 256B
        float a64 = __shfl(pre, z);
        float b   = __shfl(a, l + 1);
        if (l == 63) b = a64;
        tr[l * 33 + z] = (f16b(b - a) << 16) | f16b(a);
    }
    __syncthreads();

    // P: 64 i x 2 h x 12 dw = 1536 dw = 384 uint4 chunks, 6 iters x 64 lanes.
    #pragma unroll
    for (int it = 0; it < 6; ++it) {
        int c   = it * 64 + l;               // chunk id
        int i   = c / 6;
        int rem = c - i * 6;
        int h   = rem >= 3;
        int sch = rem - h * 3;
        int zb  = h * 16;
        uint w4[4];
        #pragma unroll
        for (int n = 0; n < 4; ++n) {
            int gdw = sch * 4 + n;           // 0..11
            if (gdw < 6) {                   // g0 pair j=gdw
                int z = zb + 2 * gdw;
                uint u0 = tr[i * 33 + z], u1 = tr[i * 33 + z + 1];
                w4[n] = (u0 & 0xffffu) | (u1 << 16);
            } else {                         // d pair j=gdw-6
                int z = zb + 2 * (gdw - 6);
                uint u0 = tr[i * 33 + z], u1 = tr[i * 33 + z + 1];
                w4[n] = (u0 >> 16) | (u1 & 0xffff0000u);
            }
        }
        uint4 o; o.x = w4[0]; o.y = w4[1]; o.z = w4[2]; o.w = w4[3];
        *(uint4*)(P + ((size_t)(v * 1024 + ib + i) * 2 + h) * 12 + sch * 4) = o;
    }

    // Q: per lane i=l: 2h x {g0 uint2, d uint2} for z in [h*16+12, h*16+16)
    #pragma unroll
    for (int h = 0; h < 2; ++h) {
        int z0 = h * 16 + 12;
        uint a0 = tr[l * 33 + z0],     a1 = tr[l * 33 + z0 + 1];
        uint a2 = tr[l * 33 + z0 + 2], a3 = tr[l * 33 + z0 + 3];
        uint2 gq, dq;
        gq.x = (a0 & 0xffffu) | (a1 << 16);
        gq.y = (a2 & 0xffffu) | (a3 << 16);
        dq.x = (a0 >> 16) | (a1 & 0xffff0000u);
        dq.y = (a2 >> 16) | (a3 & 0xffff0000u);
        size_t qb = (((size_t)v * 2 + h) * 2) * 2048 + (size_t)(ib + l) * 2;
        *(uint2*)(Q + qb)        = gq;       // k=0
        *(uint2*)(Q + qb + 2048) = dq;       // k=1
    }
}

// One VOP3P pair-op per sample: acc2 += g0pair ; acc2 += dpair * (w,w)
#define PAIR(p, G, D) do { \
    acc2[p] = __hadd2(acc2[p], u2h(G)); \
    acc2[p] = __hfma2(u2h(D), wp, acc2[p]); \
} while (0)

// 16x16 tile, z-group g in {0,1}. 12 z from double-buffered LDS (3 b128),
// 4 z direct from L1 via i-contiguous Q (2 dwordx2, ~3 lines/wave-instr).
// f16 pair accumulators, flushed to f32 every 8 views. One barrier/view.
__global__ __launch_bounds__(256, 6) void bp_hyb(const uint* __restrict__ P,
                                                 const uint* __restrict__ Q,
                                                 float* __restrict__ out) {
    __shared__ float2 cs[NVIEW];
    __shared__ int imintab[NVIEW];
    __shared__ __align__(16) uint stage[2][NR * RSTRIDE];   // 2 x 1152 B

    const int tid = threadIdx.y * BX + threadIdx.x;
    const int g   = blockIdx.z;
    const float xf0 = (float)(int)(blockIdx.x * BX) - 255.5f;
    const float yf0 = (float)(int)(blockIdx.y * BY) - 255.5f;

    for (int v = tid; v < NVIEW; v += BX * BY) {
        float th = (float)v * (float)(M_PI / NVIEW);
        float s, c;
        sincosf(th, &s, &c);
        cs[v] = make_float2(c, s);
        float b0 = fmaf(yf0, s, 511.5f);
        float b1 = fmaf(yf0 + (float)(BY - 1), s, 511.5f);
        float t00 = fmaf(xf0, c, b0);
        float t10 = fmaf(xf0 + (float)(BX - 1), c, b0);
        float t01 = fmaf(xf0, c, b1);
        float t11 = fmaf(xf0 + (float)(BX - 1), c, b1);
        imintab[v] = (int)fminf(fminf(t00, t10), fminf(t01, t11));  // exact floor(t_min)
    }
    __syncthreads();

    const int x = blockIdx.x * BX + threadIdx.x;
    const int y = blockIdx.y * BY + threadIdx.y;
    const float xf = (float)x - 255.5f;
    const float yf = (float)y - 255.5f;

    float accF[ZG];
    #pragma unroll
    for (int z = 0; z < ZG; ++z) accF[z] = 0.0f;
    __half2 acc2[8];
    #pragma unroll
    for (int p = 0; p < 8; ++p) acc2[p] = u2h(0u);

    // Staging roles: 24 rows x 3 chunks = 72 slots, 18 lanes per wave.
    const int  wv   = tid >> 6;
    const int  ln   = tid & 63;
    const bool sact = (ln < 18);
    const int  slot = wv * 18 + ln;          // 0..71
    const int  sr   = slot / 3;              // row 0..23
    const int  sch  = slot - sr * 3;         // chunk 0..2
    const int  swr  = sr * RSTRIDE + sch * 4;
    // P chunk dword offset for view vv: vv*24576 + (imintab[vv]+sr)*24 + g*12 + sch*4
    const int  sgl  = sr * 24 + g * 12 + sch * 4;   // lane-static part

    // Prologue: stage view 0; pipeline (i0,w) and direct regs for view 0.
    uint4 st;
    if (sact) {
        st = *(const uint4*)(P + (size_t)imintab[0] * 24 + sgl);
        *(uint4*)&stage[0][swr] = st;
    }
    float2 a0v = cs[0];
    float t0   = fmaf(xf, a0v.x, fmaf(yf, a0v.y, 511.5f));
    int   i0c  = (int)t0;
    float wc   = t0 - (float)i0c;
    uint2 dgc, ddc;
    {
        const uint* qb = Q + ((size_t)0 * 2 + g) * 2 * 2048 + (size_t)i0c * 2;
        dgc = *(const uint2*)(qb);
        ddc = *(const uint2*)(qb + 2048);
    }
    __syncthreads();

    for (int vb = 0; vb < NVIEW / 8; ++vb) {
        #pragma unroll
        for (int u = 0; u < 8; ++u) {
            const int v  = vb * 8 + u;
            const int vn = (v + 1 < NVIEW) ? v + 1 : NVIEW - 1;

            // [A] staging prefetch for vn (consumed at [F])
            if (sact) {
                st = *(const uint4*)(P + (size_t)vn * 24576
                                       + (size_t)imintab[vn] * 24 + sgl);
            }
            // next-view sample position (pipelined one ahead)
            float2 an = cs[vn];
            float tn  = fmaf(xf, an.x, fmaf(yf, an.y, 511.5f));
            int   i0n = (int)tn;
            float wn  = tn - (float)i0n;
            // [B] direct prefetch for vn (i-contiguous Q: ~3 lines/wave-instr)
            const uint* qb = Q + ((size_t)vn * 2 + g) * 2 * 2048 + (size_t)i0n * 2;
            uint2 dgn = *(const uint2*)(qb);
            uint2 ddn = *(const uint2*)(qb + 2048);

            // current view v samples
            __half2 wp = __float2half2_rn(wc);
            int rl = i0c - imintab[v];
            const uint* sp = &stage[v & 1][0] + rl * RSTRIDE;
            uint4 q0 = *(const uint4*)(sp);
            uint4 q1 = *(const uint4*)(sp + 4);
            uint4 q2 = *(const uint4*)(sp + 8);

            PAIR(0, q0.x, q1.z); PAIR(1, q0.y, q1.w);
            PAIR(2, q0.z, q2.x); PAIR(3, q0.w, q2.y);
            PAIR(4, q1.x, q2.z); PAIR(5, q1.y, q2.w);
            PAIR(6, dgc.x, ddc.x); PAIR(7, dgc.y, ddc.y);

            // rotate pipeline registers
            i0c = i0n; wc = wn; dgc = dgn; ddc = ddn;

            // [F] publish staging for v+1; [G] one barrier per view
            if (sact) *(uint4*)&stage[(v + 1) & 1][swr] = st;
            __syncthreads();
        }
        // flush f16 pair accumulators to f32 (every 8 views; bounds f16 error)
        #pragma unroll
        for (int p = 0; p < 8; ++p) {
            accF[2 * p]     += __low2float(acc2[p]);
            accF[2 * p + 1] += __high2float(acc2[p]);
            acc2[p] = u2h(0u);
        }
    }

    const float scale = 0.0043633231299858236f;  // pi / 720
    #pragma unroll
    for (int lz = 0; lz < ZG; ++lz) {
        out[(((size_t)(g * ZG + lz)) * NY + y) * NX + x] = accF[lz] * scale;
    }
}

// Fallback (ws too small): direct fp32, two loads per sample.
__global__ __launch_bounds__(256) void bp_direct(const float* __restrict__ xin,
                                                 float* __restrict__ out) {
    __shared__ float2 cs[NVIEW];
    int lt = threadIdx.y * 64 + threadIdx.x;
    for (int v = lt; v < NVIEW; v += 256) {
        float th = (float)v * (float)(M_PI / NVIEW);
        float s, c;
        sincosf(th, &s, &c);
        cs[v] = make_float2(c, s);
    }
    __syncthreads();

    int x = blockIdx.x * 64 + threadIdx.x;
    int y = blockIdx.y * 4 + threadIdx.y;
    float xf = (float)x - 255.5f;
    float yf = (float)y - 255.5f;

    float acc[NZ];
    #pragma unroll
    for (int z = 0; z < NZ; ++z) acc[z] = 0.0f;

    for (int v = 0; v < NVIEW; ++v) {
        float2 a = cs[v];
        float t  = fmaf(xf, a.x, fmaf(yf, a.y, 511.5f));
        int   i0 = (int)t;
        float w  = t - (float)i0;
        const float* p = xin + (size_t)v * NDCT + i0;
        #pragma unroll
        for (int z = 0; z < NZ; ++z) {
            float g0 = p[(size_t)z * NVIEW * NDCT];
            float g1 = p[(size_t)z * NVIEW * NDCT + 1];
            acc[z] += fmaf(w, g1 - g0, g0);
        }
    }

    const float scale = 0.0043633231299858236f;
    #pragma unroll
    for (int z = 0; z < NZ; ++z) {
        out[((size_t)z * NY + y) * NX + x] = acc[z] * scale;
    }
}

extern "C" void kernel_launch(void* const* d_in, const int* in_sizes, int n_in,
                              void* d_out, int out_size, void* d_ws, size_t ws_size,
                              hipStream_t stream) {
    const float* x = (const float*)d_in[0];
    float* out = (float*)d_out;

    const size_t p_dw = (size_t)NVIEW * NDCT * 24;          // 70.8 MB
    const size_t q_dw = (size_t)NVIEW * 2 * 2 * NDCT * 2;   // 23.6 MB
    const size_t need = (p_dw + q_dw) * sizeof(uint);       // 94.4 MB (same as R1-R5)

    if (ws_size >= need) {
        uint* P = (uint*)d_ws;
        uint* Q = P + p_dw;
        pack_kernel<<<dim3(NVIEW, NDCT / 64), 64, 0, stream>>>(x, P, Q);
        bp_hyb<<<dim3(NX / BX, NY / BY, 2), dim3(BX, BY), 0, stream>>>(P, Q, out);
    } else {
        bp_direct<<<dim3(NX / 64, NY / 4), dim3(64, 4), 0, stream>>>(x, out);
    }
}

// Round 7
// 813.187 us; speedup vs baseline: 9.8006x; 9.8006x over previous
//
#include <hip/hip_runtime.h>
#include <math.h>

#define NVIEW 720
#define NDCT  1024
#define NZ    32
#define NX    512
#define NY    512

#define BX 16        // block tile x
#define BY 16        // block tile y
#define ZG 16        // z per block (z-split factor 2)
#define ZLDS 12      // z from LDS (3 x ds_read_b128); 4 z direct from L1 (Q)
#define NR 24        // staged detector rows (16x16 tile i0 spread <= 22, +1 tap)
#define RSTRIDE 12   // dwords/staged row. Bank overlap only at dr in {8,16} (12*dr
                     // mod 32 == 0), 2-way pileups are free (m136/R1/R5: ~0 conflicts).

typedef unsigned int uint;

// Round fp32 -> bf16 bits (RNE).
__device__ __forceinline__ uint f2bf_rne(float f) {
    uint u = __float_as_uint(f);
    return (u + 0x7fffu + ((u >> 16) & 1u)) >> 16;
}

// Word for (v,i,z): hi16 = dithered bf16(g0=p[i]) (dither makes as_float(word)
// the best approx of g0, cancelling lo-bit junk), lo16 = bf16(d=p[i+1]-p[i]).
// Decode (3 VALU): acc += as_float(u); acc = fma(w, as_float(u<<16), acc).
__device__ __forceinline__ uint pack_word(float a, float b) {
    uint lo = f2bf_rne(b - a);
    uint u  = (f2bf_rne(a) << 16) | lo;
    uint up = u + 0x10000u, um = u - 0x10000u;
    float e0 = fabsf(__uint_as_float(u)  - a);
    float e1 = fabsf(__uint_as_float(up) - a);
    float e2 = fabsf(__uint_as_float(um) - a);
    if (e1 < e0) { u = up; e0 = e1; }
    if (e2 < e0) { u = um; }
    return u;
}

// Workspace:
//  P[((v*1024 + i)*2 + h)*12 + zl]  : z = h*16 + zl, zl in [0,12)   (70.8 MB)
//  Q[((v*2 + h)*1024 + i)*4 + (z-12)]: z in [h*16+12, h*16+16), i-contiguous
//    so the per-pixel direct load (dwordx4) spans ~5 cache lines/wave. (23.6 MB)
// Input x: (Z=32,1,NVIEW,NDCT); proj[v][z][i] = x[z][0][v][i].
__global__ __launch_bounds__(64) void pack_kernel(const float* __restrict__ x,
                                                  uint* __restrict__ P,
                                                  uint* __restrict__ Q) {
    __shared__ uint tr[64 * 33];             // [i_local][z], stride 33 -> conflict-free
    const int l  = threadIdx.x;              // 0..63
    const int v  = blockIdx.x;               // 0..719
    const int ib = blockIdx.y * 64;          // i block base
    const bool last = (ib + 64 >= NDCT);
    const float* rowbase = x + (size_t)v * NDCT + ib;

    float pre = 0.0f;                        // boundary value i=ib+64, z=lane
    if (l < NZ && !last) pre = rowbase[(size_t)l * (NVIEW * NDCT) + 64];

    for (int z = 0; z < NZ; ++z) {
        const float* r = rowbase + (size_t)z * (NVIEW * NDCT);
        float a   = r[l];                    // coalesced 256B
        float a64 = __shfl(pre, z);
        float b   = __shfl(a, l + 1);
        if (l == 63) b = a64;                // neighbor across wave boundary
        tr[l * 33 + z] = pack_word(a, b);
    }
    __syncthreads();

    // P: 64 i x 2 h x 3 chunks = 384 uint4, 6 iters x 64 lanes (coalesced).
    #pragma unroll
    for (int it = 0; it < 6; ++it) {
        int c   = it * 64 + l;
        int i   = c / 6;
        int rem = c - i * 6;
        int h   = rem >= 3;
        int sch = rem - h * 3;
        const uint* trow = &tr[i * 33 + h * 16 + sch * 4];
        uint4 o; o.x = trow[0]; o.y = trow[1]; o.z = trow[2]; o.w = trow[3];
        *(uint4*)(P + ((size_t)(v * 1024 + ib + i) * 2 + h) * 12 + sch * 4) = o;
    }
    // Q: per lane i, per h: uint4 of z = h*16+12..15 (lane-consecutive 16B, coalesced).
    #pragma unroll
    for (int h = 0; h < 2; ++h) {
        const uint* trow = &tr[l * 33 + h * 16 + 12];
        uint4 o; o.x = trow[0]; o.y = trow[1]; o.z = trow[2]; o.w = trow[3];
        *(uint4*)(Q + ((size_t)(v * 2 + h) * 1024 + ib + l) * 4) = o;
    }
}

// 3 VALU ops per sample (all scalar f32 state -- no class arrays, no spills).
#define SAMPLE(zz, uu) do { \
    acc[zz] += __uint_as_float(uu); \
    acc[zz]  = fmaf(w, __uint_as_float((uu) << 16), acc[zz]); \
} while (0)

#define DECODE_VIEW(BUF, IMIN) do { \
    float w = wc; \
    const uint* sp = &stage[BUF][0] + (i0c - (IMIN)) * RSTRIDE; \
    uint4 q0 = *(const uint4*)(sp); \
    uint4 q1 = *(const uint4*)(sp + 4); \
    uint4 q2 = *(const uint4*)(sp + 8); \
    SAMPLE( 0, q0.x); SAMPLE( 1, q0.y); SAMPLE( 2, q0.z); SAMPLE( 3, q0.w); \
    SAMPLE( 4, q1.x); SAMPLE( 5, q1.y); SAMPLE( 6, q1.z); SAMPLE( 7, q1.w); \
    SAMPLE( 8, q2.x); SAMPLE( 9, q2.y); SAMPLE(10, q2.z); SAMPLE(11, q2.w); \
    SAMPLE(12, qd.x); SAMPLE(13, qd.y); SAMPLE(14, qd.z); SAMPLE(15, qd.w); \
} while (0)

// 16x16 tile, z-group g in {0,1}. 12 z from double-buffered LDS (3 b128),
// 4 z direct from L1 via i-contiguous Q (1 dwordx4, prefetched one view ahead
// in plain registers). One barrier/view; staging prefetch at top, publish at
// bottom. Epilogue handles view 719 so the loop body has no guards.
__global__ __launch_bounds__(256, 6) void bp_split(const uint* __restrict__ P,
                                                   const uint* __restrict__ Q,
                                                   float* __restrict__ out) {
    __shared__ float2 cs[NVIEW];
    __shared__ int imintab[NVIEW];
    __shared__ __align__(16) uint stage[2][NR * RSTRIDE];   // 2 x 1152 B

    const int tid = threadIdx.y * BX + threadIdx.x;
    const int g   = blockIdx.z;
    const float xf0 = (float)(int)(blockIdx.x * BX) - 255.5f;
    const float yf0 = (float)(int)(blockIdx.y * BY) - 255.5f;

    // Per-view cos/sin + exact block-uniform floor(t_min) (same fmaf structure
    // as the per-thread t; fmaf monotone per-operand; corners cover extremes).
    for (int v = tid; v < NVIEW; v += BX * BY) {
        float th = (float)v * (float)(M_PI / NVIEW);
        float s, c;
        sincosf(th, &s, &c);
        cs[v] = make_float2(c, s);
        float b0 = fmaf(yf0, s, 511.5f);
        float b1 = fmaf(yf0 + (float)(BY - 1), s, 511.5f);
        float t00 = fmaf(xf0, c, b0);
        float t10 = fmaf(xf0 + (float)(BX - 1), c, b0);
        float t01 = fmaf(xf0, c, b1);
        float t11 = fmaf(xf0 + (float)(BX - 1), c, b1);
        imintab[v] = (int)fminf(fminf(t00, t10), fminf(t01, t11));
    }
    __syncthreads();

    const int x = blockIdx.x * BX + threadIdx.x;
    const int y = blockIdx.y * BY + threadIdx.y;
    const float xf = (float)x - 255.5f;
    const float yf = (float)y - 255.5f;

    float acc[ZG];
    #pragma unroll
    for (int z = 0; z < ZG; ++z) acc[z] = 0.0f;

    // Staging: 24 rows x 3 chunks = 72 slots, 18 lanes/wave; slot-consecutive
    // addresses are contiguous in P (coalesced) and in LDS (conflict-free).
    const int  wv   = tid >> 6;
    const int  ln   = tid & 63;
    const bool sact = (ln < 18);
    const int  slot = wv * 18 + ln;          // 0..71
    const int  sr   = slot / 3;              // row 0..23
    const int  sch  = slot - sr * 3;         // chunk 0..2
    const int  swr  = sr * RSTRIDE + sch * 4;
    const int  sgl  = sr * 24 + g * 12 + sch * 4;   // + v*24576 + imin*24
    const uint* Qg  = Q + (size_t)g * 4096;         // + v*8192 + i0*4

    // Prologue: stage view 0; prefetch view-0 direct regs.
    uint4 st;
    if (sact) {
        st = *(const uint4*)(P + (size_t)imintab[0] * 24 + sgl);
        *(uint4*)&stage[0][swr] = st;
    }
    float2 a0 = cs[0];
    float tc  = fmaf(xf, a0.x, fmaf(yf, a0.y, 511.5f));
    int   i0c = (int)tc;                     // t in [150,873] -> trunc == floor
    float wc  = tc - (float)i0c;
    uint4 qd  = *(const uint4*)(Qg + (size_t)i0c * 4);
    __syncthreads();

    #pragma unroll 2
    for (int v = 0; v < NVIEW - 1; ++v) {
        const int vn = v + 1;
        // [A] staging prefetch for vn (consumed at [F]; ~1 view of flight)
        if (sact) {
            st = *(const uint4*)(P + (size_t)vn * 24576
                                   + (size_t)imintab[vn] * 24 + sgl);
        }
        // next-view position + [B] direct prefetch (i-contiguous: ~5 lines/wave)
        float2 an = cs[vn];
        float tn  = fmaf(xf, an.x, fmaf(yf, an.y, 511.5f));
        int   i0n = (int)tn;
        float wn  = tn - (float)i0n;
        uint4 qn  = *(const uint4*)(Qg + (size_t)vn * 8192 + (size_t)i0n * 4);

        // consume current view v (qd was loaded a full iteration ago)
        DECODE_VIEW(v & 1, imintab[v]);

        // rotate pipeline registers (scalars + one uint4 -- SROA-safe)
        i0c = i0n; wc = wn; qd = qn;

        // [F] publish staging for vn; [G] one barrier per view
        if (sact) *(uint4*)&stage[vn & 1][swr] = st;
        __syncthreads();
    }
    // Epilogue: consume view 719 (published at v=718's bottom; no prefetch).
    DECODE_VIEW(1, imintab[NVIEW - 1]);

    const float scale = 0.0043633231299858236f;  // pi / 720
    #pragma unroll
    for (int lz = 0; lz < ZG; ++lz) {
        out[(((size_t)(g * ZG + lz)) * NY + y) * NX + x] = acc[lz] * scale;
    }
}

// Fallback (ws too small): direct fp32, two loads per sample.
__global__ __launch_bounds__(256) void bp_direct(const float* __restrict__ xin,
                                                 float* __restrict__ out) {
    __shared__ float2 cs[NVIEW];
    int lt = threadIdx.y * 64 + threadIdx.x;
    for (int v = lt; v < NVIEW; v += 256) {
        float th = (float)v * (float)(M_PI / NVIEW);
        float s, c;
        sincosf(th, &s, &c);
        cs[v] = make_float2(c, s);
    }
    __syncthreads();

    int x = blockIdx.x * 64 + threadIdx.x;
    int y = blockIdx.y * 4 + threadIdx.y;
    float xf = (float)x - 255.5f;
    float yf = (float)y - 255.5f;

    float acc[NZ];
    #pragma unroll
    for (int z = 0; z < NZ; ++z) acc[z] = 0.0f;

    for (int v = 0; v < NVIEW; ++v) {
        float2 a = cs[v];
        float t  = fmaf(xf, a.x, fmaf(yf, a.y, 511.5f));
        int   i0 = (int)t;
        float w  = t - (float)i0;
        const float* p = xin + (size_t)v * NDCT + i0;
        #pragma unroll
        for (int z = 0; z < NZ; ++z) {
            float g0 = p[(size_t)z * NVIEW * NDCT];
            float g1 = p[(size_t)z * NVIEW * NDCT + 1];
            acc[z] += fmaf(w, g1 - g0, g0);
        }
    }

    const float scale = 0.0043633231299858236f;
    #pragma unroll
    for (int z = 0; z < NZ; ++z) {
        out[((size_t)z * NY + y) * NX + x] = acc[z] * scale;
    }
}

extern "C" void kernel_launch(void* const* d_in, const int* in_sizes, int n_in,
                              void* d_out, int out_size, void* d_ws, size_t ws_size,
                              hipStream_t stream) {
    const float* x = (const float*)d_in[0];
    float* out = (float*)d_out;

    const size_t p_dw = (size_t)NVIEW * NDCT * 2 * 12;   // 70.8 MB
    const size_t q_dw = (size_t)NVIEW * 2 * NDCT * 4;    // 23.6 MB
    const size_t need = (p_dw + q_dw) * sizeof(uint);    // 94.4 MB (same as R1-R5)

    if (ws_size >= need) {
        uint* P = (uint*)d_ws;
        uint* Q = P + p_dw;
        pack_kernel<<<dim3(NVIEW, NDCT / 64), 64, 0, stream>>>(x, P, Q);
        bp_split<<<dim3(NX / BX, NY / BY, 2), dim3(BX, BY), 0, stream>>>(P, Q, out);
    } else {
        bp_direct<<<dim3(NX / 64, NY / 4), dim3(64, 4), 0, stream>>>(x, out);
    }
}